// Round 4
// baseline (320.004 us; speedup 1.0000x reference)
//
#include <hip/hip_runtime.h>

// NaiveFourierKANLayer: y = cos-features @ W0^T + sin-features @ W1^T + bias
// N=32768, INPUTDIM=64, OUTDIM=256, GRIDSIZE=32 -> GEMM M=32768, N=256, K=4096
//
// R4 vs R3 (190 us, latency-bound disaster) / R2 (109.9 us, best):
//  - LESSON (R3): __syncthreads drains vmcnt(0) -- register global loads can't
//    cross a barrier. B loads must be issued and consumed within ONE interval.
//  - Tile 64x128 -> 1024 blocks = 4 blocks/CU (was 2): real latency hiding.
//    __launch_bounds__(256,4) caps VGPR at 128 so 4 blocks fit.
//  - B: global->register for the CURRENT kt, issued right after the barrier;
//    A ds_reads + feature VALU sit between issue and first MFMA use.
//  - A: swizzled LDS, double-buffered (2 x 8 KB) -> ONE barrier per iter.
//    LDS instrs/block-iter: 80 (R2) -> 24.

#define IDIM 64
#define ODIM 256
#define KDIM 4096
#define MT 64
#define NT 128

typedef __attribute__((ext_vector_type(8))) unsigned short ushort8_t;
typedef __bf16 bf16x8 __attribute__((ext_vector_type(8)));
typedef float floatx4 __attribute__((ext_vector_type(4)));
typedef float floatx2 __attribute__((ext_vector_type(2)));
typedef unsigned int uintx4 __attribute__((ext_vector_type(4)));

__device__ __forceinline__ unsigned short f2bf_rne(float f) {
  unsigned int u = __float_as_uint(f);
  return (unsigned short)((u + 0x7FFFu + ((u >> 16) & 1u)) >> 16);
}

// pack two fp32 -> packed bf16 pair (lo = a, hi = b)
#if __has_builtin(__builtin_amdgcn_cvt_pk_bf16_f32)
__device__ __forceinline__ unsigned int pack2bf(float a, float b) {
  auto v = __builtin_amdgcn_cvt_pk_bf16_f32(a, b);
  unsigned int r;
  __builtin_memcpy(&r, &v, 4);
  return r;
}
#else
__device__ __forceinline__ unsigned int pack2bf(float a, float b) {
  unsigned int ua = __float_as_uint(a) + 0x8000u;  // round-half-up
  unsigned int ub = __float_as_uint(b) + 0x8000u;
  return __builtin_amdgcn_perm(ub, ua, 0x07060302u);  // {hi16(b),hi16(a)}
}
#endif

// ---- weight gather+convert: fc(2,256,64,32) fp32 -> Wr(256,4096) bf16 ----
__global__ void __launch_bounds__(256) wconv(const float* __restrict__ fc,
                                             unsigned short* __restrict__ Wr) {
  int e = (blockIdx.x * 256 + threadIdx.x) << 2;  // element idx, 4 per thread
  int o = e >> 12;
  int k = e & 4095;
  int i = k >> 6;
  int c = (k >> 5) & 1;
  int g = k & 31;  // multiple of 4
  const float4 v = *(const float4*)(fc + ((size_t)c << 19) + o * 2048 + i * 32 + g);
  ushort4 r;
  r.x = f2bf_rne(v.x);
  r.y = f2bf_rne(v.y);
  r.z = f2bf_rne(v.z);
  r.w = f2bf_rne(v.w);
  *(ushort4*)(Wr + e) = r;
}

// ---- fused feature-gen + GEMM ----
__global__ void __launch_bounds__(256, 4)
fkan_gemm(const float* __restrict__ X, const unsigned short* __restrict__ Wr,
          const float* __restrict__ bias, float* __restrict__ out) {
  // A double buffer, XOR-swizzled: granule = row*8 + (chunk ^ (row&7))
  __shared__ __align__(16) unsigned short As[2][MT * 64];  // 2 x 8 KB

  const int t = threadIdx.x;
  const int wv = t >> 6;        // wave 0..3
  const int ln = t & 63;
  const int lm = ln & 15;
  const int quad = ln >> 4;
  const int wm = wv >> 1;       // wave m-half (rows of 32)
  const int wn = wv & 1;        // wave n-half (cols of 64)
  const int m0 = blockIdx.y * MT;
  const int n0 = blockIdx.x * NT;

  // feature-staging role: 4 threads per row, each owns g-range sub*8+1..+8
  const int arow = t & 63;
  const int sub = t >> 6;  // 0..3
  const float g0f = (float)(8 * sub + 1);

  floatx4 acc[2][4];
#pragma unroll
  for (int a = 0; a < 2; ++a)
#pragma unroll
    for (int b = 0; b < 4; ++b)
      acc[a][b] = (floatx4){0.0f, 0.0f, 0.0f, 0.0f};

  const float* xrow = X + (size_t)(m0 + arow) * IDIM;
  // B-fragment base: col = n0 + wn*64 + nt*16 + lm, k-offset quad*8
  const unsigned short* bbase =
      Wr + (size_t)(n0 + wn * 64 + lm) * KDIM + quad * 8;

  // features for one row / one g-octet: [8 cos | 8 sin] bf16 -> 2 granules
  auto gen_features = [&](float xv, unsigned short* buf) {
    float u = xv * 0.15915494309189535f;  // revolutions
    float u0 = u * g0f;
    float u1 = u0 + u;
    float u2 = u + u;
    float c2 = __builtin_amdgcn_cosf(u2);
    float s2 = __builtin_amdgcn_sinf(u2);
    floatx2 C = {__builtin_amdgcn_cosf(u0), __builtin_amdgcn_cosf(u1)};
    floatx2 S = {__builtin_amdgcn_sinf(u0), __builtin_amdgcn_sinf(u1)};
    floatx2 c2v = {c2, c2};
    floatx2 s2v = {s2, s2};
    unsigned int cpk[4], spk[4];
#pragma unroll
    for (int j = 0; j < 4; ++j) {
      cpk[j] = pack2bf(C.x, C.y);  // cos((g0+2j)x), cos((g0+2j+1)x)
      spk[j] = pack2bf(S.x, S.y);
      floatx2 t1 = C * s2v;
      floatx2 t2 = S * s2v;
      C = __builtin_elementwise_fma(C, c2v, -t2);
      S = __builtin_elementwise_fma(S, c2v, t1);
    }
    uintx4* As4 = (uintx4*)buf;
    int sw = arow & 7;
    int gb = arow * 8;
    As4[gb + (sub ^ sw)] = (uintx4){cpk[0], cpk[1], cpk[2], cpk[3]};
    As4[gb + ((4 + sub) ^ sw)] = (uintx4){spk[0], spk[1], spk[2], spk[3]};
  };

  // one iteration: B loads (current kt) issued first, consumed by MFMA at the
  // end of the SAME barrier interval; feature-gen for kt+1 in between.
  auto body = [&](int kt, float xnext) {
    bf16x8 Bv[8];
#pragma unroll
    for (int nt = 0; nt < 4; ++nt)
#pragma unroll
      for (int kh = 0; kh < 2; ++kh)
        Bv[nt * 2 + kh] =
            *(const bf16x8*)(bbase + (size_t)nt * 16 * KDIM + kt * 64 + kh * 32);

    const ushort8_t* Ab = (const ushort8_t*)As[kt & 1];
    bf16x8 af[2][2];
#pragma unroll
    for (int mt = 0; mt < 2; ++mt)
#pragma unroll
      for (int kh = 0; kh < 2; ++kh) {
        int r = wm * 32 + mt * 16 + lm;
        af[mt][kh] = __builtin_bit_cast(
            bf16x8, Ab[r * 8 + ((kh * 4 + quad) ^ (r & 7))]);
      }

    gen_features(xnext, (unsigned short*)As[(kt + 1) & 1]);

#pragma unroll
    for (int kh = 0; kh < 2; ++kh)
#pragma unroll
      for (int mt = 0; mt < 2; ++mt)
#pragma unroll
        for (int nt = 0; nt < 4; ++nt)
          acc[mt][nt] = __builtin_amdgcn_mfma_f32_16x16x32_bf16(
              af[mt][kh], Bv[nt * 2 + kh], acc[mt][nt], 0, 0, 0);

    __syncthreads();  // writes(kt+1 buf) before others' reads; A dbuf safe
  };

  // ---- prologue ----
  float4 xq = *(const float4*)(xrow);
  gen_features(xq.x, As[0]);
  __syncthreads();

  // ---- main loop: 16 groups of 4 ----
  for (int q = 0; q < 16; ++q) {
    float4 xqn = (q < 15) ? *(const float4*)(xrow + 4 * q + 4) : xq;
    int kt = 4 * q;
    body(kt + 0, xq.y);
    body(kt + 1, xq.z);
    body(kt + 2, xq.w);
    body(kt + 3, xqn.x);  // kt=63: writes unused features into As[0], harmless
    xq = xqn;
  }

  // ---- epilogue: C[row][col] = acc + bias, verified C/D layout ----
#pragma unroll
  for (int nt = 0; nt < 4; ++nt) {
    int col = n0 + wn * 64 + nt * 16 + lm;
    float bv = bias[col];
#pragma unroll
    for (int mt = 0; mt < 2; ++mt) {
      int rbase = m0 + wm * 32 + mt * 16 + quad * 4;
#pragma unroll
      for (int r = 0; r < 4; ++r)
        out[(size_t)(rbase + r) * ODIM + col] = acc[mt][nt][r] + bv;
    }
  }
}

extern "C" void kernel_launch(void* const* d_in, const int* in_sizes, int n_in,
                              void* d_out, int out_size, void* d_ws, size_t ws_size,
                              hipStream_t stream) {
  const float* x = (const float*)d_in[0];
  const float* fc = (const float*)d_in[1];
  const float* bias = (const float*)d_in[2];
  float* out = (float*)d_out;
  unsigned short* Wr = (unsigned short*)d_ws;  // 2 MB of workspace

  hipLaunchKernelGGL(wconv, dim3(1024), dim3(256), 0, stream, fc, Wr);
  // grid: (N/NT, M/MT) = (2, 512)
  hipLaunchKernelGGL(fkan_gemm, dim3(2, 512), dim3(256), 0, stream, x, Wr, bias, out);
}

// Round 5
// 219.913 us; speedup vs baseline: 1.4551x; 1.4551x over previous
//
#include <hip/hip_runtime.h>

// NaiveFourierKANLayer: y = cos-features @ W0^T + sin-features @ W1^T + bias
// N=32768, INPUTDIM=64, OUTDIM=256, GRIDSIZE=32 -> GEMM M=32768, N=256, K=4096
//
// R5 = R2 structure (best: 109.9 us) + full LDS double-buffering:
//  - LESSONS: R3/R4 proved per-lane register loads of B cannot survive the
//    barrier (vmcnt(0) drain) and starve the allocator. Keep global_load_lds.
//  - A and B tiles both double-buffered (2 x 16 KB each, 64 KB total) ->
//    ONE barrier per iteration, and the gl_lds prefetch for kt+1 is issued at
//    the TOP of iter kt: a full iteration of MFMA+VALU sits between issue and
//    the barrier's vmcnt drain -> drain is free (true async prefetch).
//  - All 16 fragment ds_reads hoisted before feature-gen (max load-use dist).
//  - x loaded as rolling float4 (1 coalesced load / 4 iters).

#define IDIM 64
#define ODIM 256
#define KDIM 4096

typedef __attribute__((ext_vector_type(8))) unsigned short ushort8_t;
typedef __bf16 bf16x8 __attribute__((ext_vector_type(8)));
typedef float floatx4 __attribute__((ext_vector_type(4)));
typedef float floatx2 __attribute__((ext_vector_type(2)));
typedef unsigned int uintx4 __attribute__((ext_vector_type(4)));

__device__ __forceinline__ unsigned short f2bf_rne(float f) {
  unsigned int u = __float_as_uint(f);
  return (unsigned short)((u + 0x7FFFu + ((u >> 16) & 1u)) >> 16);
}

// pack two fp32 -> packed bf16 pair (lo = a, hi = b)
#if __has_builtin(__builtin_amdgcn_cvt_pk_bf16_f32)
__device__ __forceinline__ unsigned int pack2bf(float a, float b) {
  auto v = __builtin_amdgcn_cvt_pk_bf16_f32(a, b);
  unsigned int r;
  __builtin_memcpy(&r, &v, 4);
  return r;
}
#else
__device__ __forceinline__ unsigned int pack2bf(float a, float b) {
  unsigned int ua = __float_as_uint(a) + 0x8000u;  // round-half-up
  unsigned int ub = __float_as_uint(b) + 0x8000u;
  return __builtin_amdgcn_perm(ub, ua, 0x07060302u);  // {hi16(b),hi16(a)}
}
#endif

__device__ __forceinline__ void gl_lds16(const void* g, void* l) {
  __builtin_amdgcn_global_load_lds(
      (__attribute__((address_space(1))) void*)g,
      (__attribute__((address_space(3))) void*)l, 16, 0, 0);
}

// ---- weight gather+convert: fc(2,256,64,32) fp32 -> Wr(256,4096) bf16 ----
__global__ void __launch_bounds__(256) wconv(const float* __restrict__ fc,
                                             unsigned short* __restrict__ Wr) {
  int e = (blockIdx.x * 256 + threadIdx.x) << 2;  // element idx, 4 per thread
  int o = e >> 12;
  int k = e & 4095;
  int i = k >> 6;
  int c = (k >> 5) & 1;
  int g = k & 31;  // multiple of 4
  const float4 v = *(const float4*)(fc + ((size_t)c << 19) + o * 2048 + i * 32 + g);
  ushort4 r;
  r.x = f2bf_rne(v.x);
  r.y = f2bf_rne(v.y);
  r.z = f2bf_rne(v.z);
  r.w = f2bf_rne(v.w);
  *(ushort4*)(Wr + e) = r;
}

// ---- fused feature-gen + GEMM ----
__global__ void __launch_bounds__(256)
fkan_gemm(const float* __restrict__ X, const unsigned short* __restrict__ Wr,
          const float* __restrict__ bias, float* __restrict__ out) {
  // XOR-swizzled tiles: granule = row*8 + (chunk ^ (row&7)); double-buffered
  __shared__ __align__(16) unsigned short As[2][128 * 64];  // 2 x 16 KB
  __shared__ __align__(16) unsigned short Bs[2][128 * 64];  // 2 x 16 KB

  const int t = threadIdx.x;
  const int wv = t >> 6;        // wave 0..3
  const int ln = t & 63;
  const int lm = ln & 15;
  const int quad = ln >> 4;
  const int wm = wv >> 1;       // wave m-half
  const int wn = wv & 1;        // wave n-half
  const int m0 = blockIdx.y * 128;
  const int n0 = blockIdx.x * 128;

  // A-staging role: one row per thread, half of g-range per p
  const int arow = t & 127;
  const int p = t >> 7;  // 0: g=1..16, 1: g=17..32
  const float gstart = (float)(16 * p + 1);

  // B-staging: swizzled source so LDS image granule l holds
  // (row = l>>3, chunk = (l&7)^((l>>3)&7))
  const int brow_off = ln >> 3;
  const int bchunk = (ln & 7) ^ ((ln >> 3) & 7);

  floatx4 acc[4][4];
#pragma unroll
  for (int a = 0; a < 4; ++a)
#pragma unroll
    for (int b = 0; b < 4; ++b)
      acc[a][b] = (floatx4){0.0f, 0.0f, 0.0f, 0.0f};

  const float* xrow = X + (size_t)(m0 + arow) * IDIM;

  // async B staging for iter kt into buffer buf
  auto glB = [&](int kt, int buf) {
#pragma unroll
    for (int j = 0; j < 4; ++j) {
      int region = wv * 4 + j;             // 16 regions x 1KB
      int rowB = region * 8 + brow_off;
      const unsigned short* gsrc =
          Wr + (size_t)(n0 + rowB) * KDIM + kt * 64 + bchunk * 8;
      gl_lds16(gsrc, Bs[buf] + region * 512);  // lane l -> +l*16 bytes
    }
  };

  // features for iter's input dim: [cos g=1..32 | sin g=1..32] per row
  auto gen_features = [&](float xv, unsigned short* buf) {
    float u = xv * 0.15915494309189535f;  // revolutions
    float u0 = u * gstart;
    float u1 = u0 + u;
    float u2 = u + u;
    float c2 = __builtin_amdgcn_cosf(u2);
    float s2 = __builtin_amdgcn_sinf(u2);
    floatx2 C = {__builtin_amdgcn_cosf(u0), __builtin_amdgcn_cosf(u1)};
    floatx2 S = {__builtin_amdgcn_sinf(u0), __builtin_amdgcn_sinf(u1)};
    floatx2 c2v = {c2, c2};
    floatx2 s2v = {s2, s2};
    unsigned int cpk[8], spk[8];
#pragma unroll
    for (int j = 0; j < 8; ++j) {
      cpk[j] = pack2bf(C.x, C.y);
      spk[j] = pack2bf(S.x, S.y);
      floatx2 t1 = C * s2v;
      floatx2 t2 = S * s2v;
      C = __builtin_elementwise_fma(C, c2v, -t2);
      S = __builtin_elementwise_fma(S, c2v, t1);
    }
    uintx4* As4 = (uintx4*)buf;
    int sw = arow & 7;
    int gb = arow * 8;
    As4[gb + ((2 * p) ^ sw)] = (uintx4){cpk[0], cpk[1], cpk[2], cpk[3]};
    As4[gb + ((2 * p + 1) ^ sw)] = (uintx4){cpk[4], cpk[5], cpk[6], cpk[7]};
    As4[gb + ((4 + 2 * p) ^ sw)] = (uintx4){spk[0], spk[1], spk[2], spk[3]};
    As4[gb + ((5 + 2 * p) ^ sw)] = (uintx4){spk[4], spk[5], spk[6], spk[7]};
  };

  // one iteration: prefetch kt+1 (async B + computed A) while computing kt
  auto body = [&](int kt, float xnext, bool do_next) {
    int cur = kt & 1, nxt = cur ^ 1;
    if (do_next) glB(kt + 1, nxt);  // in flight for the whole iteration

    // hoist ALL current-iter fragment reads (max load->use distance)
    bf16x8 af[4][2], bfr[4][2];
    const ushort8_t* Ab = (const ushort8_t*)As[cur];
    const ushort8_t* Bb = (const ushort8_t*)Bs[cur];
#pragma unroll
    for (int mt = 0; mt < 4; ++mt)
#pragma unroll
      for (int kh = 0; kh < 2; ++kh) {
        int r = wm * 64 + mt * 16 + lm;
        af[mt][kh] = __builtin_bit_cast(
            bf16x8, Ab[r * 8 + ((kh * 4 + quad) ^ (r & 7))]);
      }
#pragma unroll
    for (int nt = 0; nt < 4; ++nt)
#pragma unroll
      for (int kh = 0; kh < 2; ++kh) {
        int n = wn * 64 + nt * 16 + lm;
        bfr[nt][kh] = __builtin_bit_cast(
            bf16x8, Bb[n * 8 + ((kh * 4 + quad) ^ (n & 7))]);
      }

    if (do_next) gen_features(xnext, (unsigned short*)As[nxt]);

#pragma unroll
    for (int kh = 0; kh < 2; ++kh)
#pragma unroll
      for (int mt = 0; mt < 4; ++mt)
#pragma unroll
        for (int nt = 0; nt < 4; ++nt)
          acc[mt][nt] = __builtin_amdgcn_mfma_f32_16x16x32_bf16(
              af[mt][kh], bfr[nt][kh], acc[mt][nt], 0, 0, 0);

    __syncthreads();  // single barrier: next-iter bufs ready, cur-bufs released
  };

  // ---- prologue: stage kt=0 ----
  float4 xq = *(const float4*)(xrow);
  gen_features(xq.x, As[0]);
  glB(0, 0);
  __syncthreads();  // drains prologue gl_lds (one-time ~200 cyc)

  // ---- main loop: 16 groups of 4 ----
  for (int q = 0; q < 16; ++q) {
    float4 xqn = (q < 15) ? *(const float4*)(xrow + 4 * q + 4) : xq;
    int kt = 4 * q;
    body(kt + 0, xq.y, true);
    body(kt + 1, xq.z, true);
    body(kt + 2, xq.w, true);
    body(kt + 3, xqn.x, q < 15);
    xq = xqn;
  }

  // ---- epilogue: C[row][col] = acc + bias, verified C/D layout ----
#pragma unroll
  for (int nt = 0; nt < 4; ++nt) {
    int col = n0 + wn * 64 + nt * 16 + lm;
    float bv = bias[col];
#pragma unroll
    for (int mt = 0; mt < 4; ++mt) {
      int rbase = m0 + wm * 64 + mt * 16 + quad * 4;
#pragma unroll
      for (int r = 0; r < 4; ++r)
        out[(size_t)(rbase + r) * ODIM + col] = acc[mt][nt][r] + bv;
    }
  }
}

extern "C" void kernel_launch(void* const* d_in, const int* in_sizes, int n_in,
                              void* d_out, int out_size, void* d_ws, size_t ws_size,
                              hipStream_t stream) {
  const float* x = (const float*)d_in[0];
  const float* fc = (const float*)d_in[1];
  const float* bias = (const float*)d_in[2];
  float* out = (float*)d_out;
  unsigned short* Wr = (unsigned short*)d_ws;  // 2 MB of workspace

  hipLaunchKernelGGL(wconv, dim3(1024), dim3(256), 0, stream, fc, Wr);
  // grid: (N/128, M/128) = (2, 256)
  hipLaunchKernelGGL(fkan_gemm, dim3(2, 256), dim3(256), 0, stream, x, Wr, bias, out);
}

// Round 6
// 193.426 us; speedup vs baseline: 1.6544x; 1.1369x over previous
//
#include <hip/hip_runtime.h>

// NaiveFourierKANLayer: y = cos-features @ W0^T + sin-features @ W1^T + bias
// N=32768, INPUTDIM=64, OUTDIM=256, GRIDSIZE=32 -> GEMM M=32768, N=256, K=4096
//
// R6 = R2 inner structure (best: 109.9 us) + 2-way K-split for occupancy:
//  - LESSONS R3-R5: register B loads, aggressive launch_bounds, and LDS
//    double-buffering all regressed (latency exposure / occupancy collapse).
//    The R2 single-buffered 32KB 2-barrier loop is the local optimum; its
//    limiter is 2 blocks/CU of overlap (no pipe >46% busy).
//  - K-split: blockIdx.z in {0,1} handles input dims [32*kz, 32*kz+32).
//    Grid 1024 = 4 blocks/CU. Partial sums combined with unsafeAtomicAdd
//    (native global_atomic_add_f32, device scope). bias_fill pre-initializes
//    out = bias (harness re-poisons out each launch, so this runs every call).

#define IDIM 64
#define ODIM 256
#define KDIM 4096

typedef __attribute__((ext_vector_type(8))) unsigned short ushort8_t;
typedef __bf16 bf16x8 __attribute__((ext_vector_type(8)));
typedef float floatx4 __attribute__((ext_vector_type(4)));
typedef float floatx2 __attribute__((ext_vector_type(2)));
typedef unsigned int uintx4 __attribute__((ext_vector_type(4)));

__device__ __forceinline__ unsigned short f2bf_rne(float f) {
  unsigned int u = __float_as_uint(f);
  return (unsigned short)((u + 0x7FFFu + ((u >> 16) & 1u)) >> 16);
}

// pack two fp32 -> packed bf16 pair (lo = a, hi = b)
#if __has_builtin(__builtin_amdgcn_cvt_pk_bf16_f32)
__device__ __forceinline__ unsigned int pack2bf(float a, float b) {
  auto v = __builtin_amdgcn_cvt_pk_bf16_f32(a, b);
  unsigned int r;
  __builtin_memcpy(&r, &v, 4);
  return r;
}
#else
__device__ __forceinline__ unsigned int pack2bf(float a, float b) {
  unsigned int ua = __float_as_uint(a) + 0x8000u;  // round-half-up
  unsigned int ub = __float_as_uint(b) + 0x8000u;
  return __builtin_amdgcn_perm(ub, ua, 0x07060302u);  // {hi16(b),hi16(a)}
}
#endif

__device__ __forceinline__ void gl_lds16(const void* g, void* l) {
  __builtin_amdgcn_global_load_lds(
      (__attribute__((address_space(1))) void*)g,
      (__attribute__((address_space(3))) void*)l, 16, 0, 0);
}

// ---- out = bias (broadcast); also the zero-init for the atomic epilogue ----
__global__ void __launch_bounds__(256) bias_fill(const float* __restrict__ bias,
                                                 float* __restrict__ out) {
  int idx = blockIdx.x * 256 + threadIdx.x;      // float4 index
  float4 b = ((const float4*)bias)[idx & 63];    // ODIM/4 = 64 groups
  ((float4*)out)[idx] = b;
}

// ---- weight gather+convert: fc(2,256,64,32) fp32 -> Wr(256,4096) bf16 ----
__global__ void __launch_bounds__(256) wconv(const float* __restrict__ fc,
                                             unsigned short* __restrict__ Wr) {
  int e = (blockIdx.x * 256 + threadIdx.x) << 2;  // element idx, 4 per thread
  int o = e >> 12;
  int k = e & 4095;
  int i = k >> 6;
  int c = (k >> 5) & 1;
  int g = k & 31;  // multiple of 4
  const float4 v = *(const float4*)(fc + ((size_t)c << 19) + o * 2048 + i * 32 + g);
  ushort4 r;
  r.x = f2bf_rne(v.x);
  r.y = f2bf_rne(v.y);
  r.z = f2bf_rne(v.z);
  r.w = f2bf_rne(v.w);
  *(ushort4*)(Wr + e) = r;
}

// ---- fused feature-gen + GEMM (R2 loop, K-split via blockIdx.z) ----
__global__ void __launch_bounds__(256)
fkan_gemm(const float* __restrict__ X, const unsigned short* __restrict__ Wr,
          float* __restrict__ out) {
  // XOR-swizzled tiles: granule = row*8 + (chunk ^ (row&7))
  __shared__ __align__(16) unsigned short As[128 * 64];  // 16 KB
  __shared__ __align__(16) unsigned short Bs[128 * 64];  // 16 KB

  const int t = threadIdx.x;
  const int wv = t >> 6;        // wave 0..3
  const int ln = t & 63;
  const int lm = ln & 15;
  const int quad = ln >> 4;
  const int wm = wv >> 1;       // wave m-half
  const int wn = wv & 1;        // wave n-half
  const int m0 = blockIdx.y * 128;
  const int n0 = blockIdx.x * 128;
  const int kt0 = blockIdx.z * 32;  // this block's input-dim range

  // A-staging role: one row per thread, half of g-range per p
  const int arow = t & 127;
  const int p = t >> 7;  // 0: g=1..16, 1: g=17..32
  const float gstart = (float)(16 * p + 1);

  // B-staging: swizzled source so LDS image granule l holds
  // (row = l>>3, chunk = (l&7)^((l>>3)&7))
  const int brow_off = ln >> 3;
  const int bchunk = (ln & 7) ^ ((ln >> 3) & 7);

  floatx4 acc[4][4];
#pragma unroll
  for (int a = 0; a < 4; ++a)
#pragma unroll
    for (int b = 0; b < 4; ++b)
      acc[a][b] = (floatx4){0.0f, 0.0f, 0.0f, 0.0f};

  const float* xrow = X + (size_t)(m0 + arow) * IDIM;

  // async B staging for input dim kt
  auto glB = [&](int kt) {
#pragma unroll
    for (int j = 0; j < 4; ++j) {
      int region = wv * 4 + j;             // 16 regions x 1KB
      int rowB = region * 8 + brow_off;
      const unsigned short* gsrc =
          Wr + (size_t)(n0 + rowB) * KDIM + kt * 64 + bchunk * 8;
      gl_lds16(gsrc, Bs + region * 512);   // lane l -> +l*16 bytes
    }
  };

  // features for input dim: [cos g=1..32 | sin g=1..32] per row
  auto gen_features = [&](float xv) {
    float u = xv * 0.15915494309189535f;  // revolutions
    float u0 = u * gstart;
    float u1 = u0 + u;
    float u2 = u + u;
    float c2 = __builtin_amdgcn_cosf(u2);
    float s2 = __builtin_amdgcn_sinf(u2);
    floatx2 C = {__builtin_amdgcn_cosf(u0), __builtin_amdgcn_cosf(u1)};
    floatx2 S = {__builtin_amdgcn_sinf(u0), __builtin_amdgcn_sinf(u1)};
    floatx2 c2v = {c2, c2};
    floatx2 s2v = {s2, s2};
    unsigned int cpk[8], spk[8];
#pragma unroll
    for (int j = 0; j < 8; ++j) {
      cpk[j] = pack2bf(C.x, C.y);
      spk[j] = pack2bf(S.x, S.y);
      floatx2 t1 = C * s2v;
      floatx2 t2 = S * s2v;
      C = __builtin_elementwise_fma(C, c2v, -t2);
      S = __builtin_elementwise_fma(S, c2v, t1);
    }
    uintx4* As4 = (uintx4*)As;
    int sw = arow & 7;
    int gb = arow * 8;
    As4[gb + ((2 * p) ^ sw)] = (uintx4){cpk[0], cpk[1], cpk[2], cpk[3]};
    As4[gb + ((2 * p + 1) ^ sw)] = (uintx4){cpk[4], cpk[5], cpk[6], cpk[7]};
    As4[gb + ((4 + 2 * p) ^ sw)] = (uintx4){spk[0], spk[1], spk[2], spk[3]};
    As4[gb + ((5 + 2 * p) ^ sw)] = (uintx4){spk[4], spk[5], spk[6], spk[7]};
  };

  auto body = [&](int kt, float xv) {
    glB(kt);             // async B for this iter, flies under feature VALU
    gen_features(xv);    // A features for this iter
    __syncthreads();     // both tiles ready

#pragma unroll
    for (int kh = 0; kh < 2; ++kh) {
      bf16x8 af[4], bfr[4];
#pragma unroll
      for (int mt = 0; mt < 4; ++mt) {
        int r = wm * 64 + mt * 16 + lm;
        af[mt] = __builtin_bit_cast(
            bf16x8, ((const ushort8_t*)As)[r * 8 + ((kh * 4 + quad) ^ (r & 7))]);
      }
#pragma unroll
      for (int nt = 0; nt < 4; ++nt) {
        int n = wn * 64 + nt * 16 + lm;
        bfr[nt] = __builtin_bit_cast(
            bf16x8, ((const ushort8_t*)Bs)[n * 8 + ((kh * 4 + quad) ^ (n & 7))]);
      }
#pragma unroll
      for (int mt = 0; mt < 4; ++mt)
#pragma unroll
        for (int nt = 0; nt < 4; ++nt)
          acc[mt][nt] = __builtin_amdgcn_mfma_f32_16x16x32_bf16(
              af[mt], bfr[nt], acc[mt][nt], 0, 0, 0);
    }

    __syncthreads();     // tiles consumed, safe to restage
  };

  // ---- main loop: 8 groups of 4 input dims ----
  float4 xq = *(const float4*)(xrow + kt0);
  for (int q = 0; q < 8; ++q) {
    float4 xqn = (q < 7) ? *(const float4*)(xrow + kt0 + 4 * q + 4) : xq;
    int kt = kt0 + 4 * q;
    body(kt + 0, xq.x);
    body(kt + 1, xq.y);
    body(kt + 2, xq.z);
    body(kt + 3, xq.w);
    xq = xqn;
  }

  // ---- epilogue: atomic accumulate into out (bias pre-filled) ----
#pragma unroll
  for (int nt = 0; nt < 4; ++nt) {
    int col = n0 + wn * 64 + nt * 16 + lm;
#pragma unroll
    for (int mt = 0; mt < 4; ++mt) {
      int rbase = m0 + wm * 64 + mt * 16 + quad * 4;
#pragma unroll
      for (int r = 0; r < 4; ++r)
        unsafeAtomicAdd(out + (size_t)(rbase + r) * ODIM + col, acc[mt][nt][r]);
    }
  }
}

extern "C" void kernel_launch(void* const* d_in, const int* in_sizes, int n_in,
                              void* d_out, int out_size, void* d_ws, size_t ws_size,
                              hipStream_t stream) {
  const float* x = (const float*)d_in[0];
  const float* fc = (const float*)d_in[1];
  const float* bias = (const float*)d_in[2];
  float* out = (float*)d_out;
  unsigned short* Wr = (unsigned short*)d_ws;  // 2 MB of workspace

  // out = bias broadcast (8.4M floats = 2M float4)
  hipLaunchKernelGGL(bias_fill, dim3((32768 * 256 / 4) / 256), dim3(256), 0,
                     stream, bias, out);
  hipLaunchKernelGGL(wconv, dim3(1024), dim3(256), 0, stream, fc, Wr);
  // grid: (N/128, M/128, K-split) = (2, 256, 2) = 1024 blocks = 4/CU
  hipLaunchKernelGGL(fkan_gemm, dim3(2, 256, 2), dim3(256), 0, stream, x, Wr, out);
}

// Round 7
// 165.269 us; speedup vs baseline: 1.9363x; 1.1704x over previous
//
#include <hip/hip_runtime.h>

// NaiveFourierKANLayer: y = cos-features @ W0^T + sin-features @ W1^T + bias
// N=32768, INPUTDIM=64, OUTDIM=256, GRIDSIZE=32 -> GEMM M=32768, N=256, K=4096
//
// R7: half-slab software pipeline inside the 32 KB LDS budget.
//  - EMPIRICAL (R2/R4/R5/R6 occupancy): concurrently allocatable LDS is
//    ~64 KB/CU on this part (blocks/CU = min(grid/CU, 64KB/LDS)). 32 KB
//    keeps 2 blocks/CU; 64 KB would halve residency (R5). So double-buffer
//    at HALF-slab (BK=32) granularity: A[2][128x32] + B[2][128x32] = 32 KB.
//  - Each input dim = 2 half-intervals (cos phase / sin phase). Per interval:
//    glB prefetch for h+1 into the idle B slab (issued a FULL interval before
//    the barrier that drains it -> drain ~free; fixes R3/R4's short prefetch
//    distance), one A-slab write (cos at gen time; sin held in 8 VGPRs and
//    written next interval), 8 ds_read_b128, 16 MFMAs, ONE barrier.
//  - Swizzle sel(r) = (r^(r>>2))&3: all b128 reads/writes spread 8-per-bank.
//  - R6's atomics + bias_fill reverted (direct-store epilogue).

#define IDIM 64
#define ODIM 256
#define KDIM 4096

typedef __attribute__((ext_vector_type(8))) unsigned short ushort8_t;
typedef __bf16 bf16x8 __attribute__((ext_vector_type(8)));
typedef float floatx4 __attribute__((ext_vector_type(4)));
typedef float floatx2 __attribute__((ext_vector_type(2)));
typedef unsigned int uintx4 __attribute__((ext_vector_type(4)));

__device__ __forceinline__ unsigned short f2bf_rne(float f) {
  unsigned int u = __float_as_uint(f);
  return (unsigned short)((u + 0x7FFFu + ((u >> 16) & 1u)) >> 16);
}

// pack two fp32 -> packed bf16 pair (lo = a, hi = b)
#if __has_builtin(__builtin_amdgcn_cvt_pk_bf16_f32)
__device__ __forceinline__ unsigned int pack2bf(float a, float b) {
  auto v = __builtin_amdgcn_cvt_pk_bf16_f32(a, b);
  unsigned int r;
  __builtin_memcpy(&r, &v, 4);
  return r;
}
#else
__device__ __forceinline__ unsigned int pack2bf(float a, float b) {
  unsigned int ua = __float_as_uint(a) + 0x8000u;  // round-half-up
  unsigned int ub = __float_as_uint(b) + 0x8000u;
  return __builtin_amdgcn_perm(ub, ua, 0x07060302u);  // {hi16(b),hi16(a)}
}
#endif

__device__ __forceinline__ void gl_lds16(const void* g, void* l) {
  __builtin_amdgcn_global_load_lds(
      (__attribute__((address_space(1))) void*)g,
      (__attribute__((address_space(3))) void*)l, 16, 0, 0);
}

// ---- weight gather+convert: fc(2,256,64,32) fp32 -> Wr(256,4096) bf16 ----
__global__ void __launch_bounds__(256) wconv(const float* __restrict__ fc,
                                             unsigned short* __restrict__ Wr) {
  int e = (blockIdx.x * 256 + threadIdx.x) << 2;  // element idx, 4 per thread
  int o = e >> 12;
  int k = e & 4095;
  int i = k >> 6;
  int c = (k >> 5) & 1;
  int g = k & 31;  // multiple of 4
  const float4 v = *(const float4*)(fc + ((size_t)c << 19) + o * 2048 + i * 32 + g);
  ushort4 r;
  r.x = f2bf_rne(v.x);
  r.y = f2bf_rne(v.y);
  r.z = f2bf_rne(v.z);
  r.w = f2bf_rne(v.w);
  *(ushort4*)(Wr + e) = r;
}

// ---- fused feature-gen + GEMM, half-slab pipelined ----
__global__ void __launch_bounds__(256)
fkan_gemm(const float* __restrict__ X, const unsigned short* __restrict__ Wr,
          const float* __restrict__ bias, float* __restrict__ out) {
  // Half-slabs (BK=32). Granule (16B) index within a slab:
  //   row*4 + (chunk ^ sel(row)),  sel(r) = (r ^ (r>>2)) & 3
  __shared__ __align__(16) unsigned short A2[2][128 * 32];  // 2 x 8 KB
  __shared__ __align__(16) unsigned short B2[2][128 * 32];  // 2 x 8 KB

  const int t = threadIdx.x;
  const int wv = t >> 6;        // wave 0..3
  const int ln = t & 63;
  const int lm = ln & 15;
  const int quad = ln >> 4;
  const int wm = wv >> 1;       // wave m-half
  const int wn = wv & 1;        // wave n-half
  const int m0 = blockIdx.y * 128;
  const int n0 = blockIdx.x * 128;

  // A-staging role: one row per thread, g-octet-pair per p
  const int arow = t & 127;
  const int p = t >> 7;  // 0: g=1..16, 1: g=17..32
  const float gstart = (float)(16 * p + 1);
  const int asel = (arow ^ (arow >> 2)) & 3;
  const int awr0 = arow * 4 + ((2 * p) ^ asel);      // cos/sin k 16p..16p+7
  const int awr1 = arow * 4 + ((2 * p + 1) ^ asel);  // k 16p+8..16p+15

  // B-staging: gl_lds forces granule = base + lane; choose SOURCE chunk so
  // the LDS image is swizzle-consistent: image (row,cimg) holds sc=cimg^sel(row)
  const int g0i = wv * 128 + ln;  // issue-0 granule
  const int g1i = g0i + 64;       // issue-1 granule
  const int br0 = g0i >> 2, br1 = g1i >> 2;
  const int bc0 = (g0i & 3) ^ ((br0 ^ (br0 >> 2)) & 3);
  const int bc1 = (g1i & 3) ^ ((br1 ^ (br1 >> 2)) & 3);
  const unsigned short* bsrc0 = Wr + (size_t)(n0 + br0) * KDIM + bc0 * 8;
  const unsigned short* bsrc1 = Wr + (size_t)(n0 + br1) * KDIM + bc1 * 8;
  const int bdst0 = (wv * 2 + 0) * 512;  // ushort offset of issue-0 region
  const int bdst1 = (wv * 2 + 1) * 512;

  // loop-invariant fragment granule indices
  int ar_idx[4], bn_idx[4];
#pragma unroll
  for (int mt = 0; mt < 4; ++mt) {
    int r = wm * 64 + mt * 16 + lm;
    ar_idx[mt] = r * 4 + (quad ^ ((r ^ (r >> 2)) & 3));
  }
#pragma unroll
  for (int nt = 0; nt < 4; ++nt) {
    int n = wn * 64 + nt * 16 + lm;
    bn_idx[nt] = n * 4 + (quad ^ ((n ^ (n >> 2)) & 3));
  }

  floatx4 acc[4][4];
#pragma unroll
  for (int a = 0; a < 4; ++a)
#pragma unroll
    for (int b = 0; b < 4; ++b)
      acc[a][b] = (floatx4){0.0f, 0.0f, 0.0f, 0.0f};

  const float* xrow = X + (size_t)(m0 + arow) * IDIM;

  // held sin payload (written one interval after gen)
  uintx4 hs0, hs1;

  // stage B phase h into slab s (koff within row = h*32 + sc*8)
  auto glB = [&](int h, int s) {
    gl_lds16(bsrc0 + h * 32, B2[s] + bdst0);
    gl_lds16(bsrc1 + h * 32, B2[s] + bdst1);
  };

  // gen features for one dim: write cos -> A2[0], hold sin in hs0/hs1
  auto gen = [&](float xv) {
    float u = xv * 0.15915494309189535f;  // revolutions
    float u0 = u * gstart;
    float u1 = u0 + u;
    float u2 = u + u;
    float c2 = __builtin_amdgcn_cosf(u2);
    float s2 = __builtin_amdgcn_sinf(u2);
    floatx2 C = {__builtin_amdgcn_cosf(u0), __builtin_amdgcn_cosf(u1)};
    floatx2 S = {__builtin_amdgcn_sinf(u0), __builtin_amdgcn_sinf(u1)};
    floatx2 c2v = {c2, c2};
    floatx2 s2v = {s2, s2};
    unsigned int cpk[8], spk[8];
#pragma unroll
    for (int j = 0; j < 8; ++j) {
      cpk[j] = pack2bf(C.x, C.y);
      spk[j] = pack2bf(S.x, S.y);
      floatx2 t1 = C * s2v;
      floatx2 t2 = S * s2v;
      C = __builtin_elementwise_fma(C, c2v, -t2);
      S = __builtin_elementwise_fma(S, c2v, t1);
    }
    uintx4* A0 = (uintx4*)A2[0];
    A0[awr0] = (uintx4){cpk[0], cpk[1], cpk[2], cpk[3]};
    A0[awr1] = (uintx4){cpk[4], cpk[5], cpk[6], cpk[7]};
    hs0 = (uintx4){spk[0], spk[1], spk[2], spk[3]};
    hs1 = (uintx4){spk[4], spk[5], spk[6], spk[7]};
  };

  // 16 MFMAs on slab s
  auto half = [&](int s) {
    const ushort8_t* Ab = (const ushort8_t*)A2[s];
    const ushort8_t* Bb = (const ushort8_t*)B2[s];
    bf16x8 af[4], bfr[4];
#pragma unroll
    for (int mt = 0; mt < 4; ++mt)
      af[mt] = __builtin_bit_cast(bf16x8, Ab[ar_idx[mt]]);
#pragma unroll
    for (int nt = 0; nt < 4; ++nt)
      bfr[nt] = __builtin_bit_cast(bf16x8, Bb[bn_idx[nt]]);
#pragma unroll
    for (int mt = 0; mt < 4; ++mt)
#pragma unroll
      for (int nt = 0; nt < 4; ++nt)
        acc[mt][nt] = __builtin_amdgcn_mfma_f32_16x16x32_bf16(
            af[mt], bfr[nt], acc[mt][nt], 0, 0, 0);
  };

  // one dim = even half (cos, slab 0) + odd half (sin, slab 1)
  auto dimbody = [&](int d, float xnext, bool do_gen) {
    // even half-interval h = 2d
    glB(2 * d + 1, 1);  // prefetch odd phase (full interval before its drain)
    {                   // write held sin(d) -> A2[1] (read next interval)
      uintx4* A1 = (uintx4*)A2[1];
      A1[awr0] = hs0;
      A1[awr1] = hs1;
    }
    half(0);
    __syncthreads();
    // odd half-interval h = 2d+1
    if (do_gen) {
      glB(2 * d + 2, 0);  // prefetch next dim's cos phase
      gen(xnext);         // cos(d+1) -> A2[0], hold sin(d+1)
    }
    half(1);
    __syncthreads();
  };

  // ---- prologue ----
  float4 xq = *(const float4*)(xrow);
  gen(xq.x);   // cos(0) -> A2[0], hold sin(0)
  glB(0, 0);
  __syncthreads();

  // ---- main loop: 16 groups of 4 dims ----
  for (int q = 0; q < 16; ++q) {
    float4 xqn = (q < 15) ? *(const float4*)(xrow + 4 * q + 4) : xq;
    int d = 4 * q;
    dimbody(d + 0, xq.y, true);
    dimbody(d + 1, xq.z, true);
    dimbody(d + 2, xq.w, true);
    dimbody(d + 3, xqn.x, q < 15);
    xq = xqn;
  }

  // ---- epilogue: C[row][col] = acc + bias, verified C/D layout ----
#pragma unroll
  for (int nt = 0; nt < 4; ++nt) {
    int col = n0 + wn * 64 + nt * 16 + lm;
    float bv = bias[col];
#pragma unroll
    for (int mt = 0; mt < 4; ++mt) {
      int rbase = m0 + wm * 64 + mt * 16 + quad * 4;
#pragma unroll
      for (int r = 0; r < 4; ++r)
        out[(size_t)(rbase + r) * ODIM + col] = acc[mt][nt][r] + bv;
    }
  }
}

extern "C" void kernel_launch(void* const* d_in, const int* in_sizes, int n_in,
                              void* d_out, int out_size, void* d_ws, size_t ws_size,
                              hipStream_t stream) {
  const float* x = (const float*)d_in[0];
  const float* fc = (const float*)d_in[1];
  const float* bias = (const float*)d_in[2];
  float* out = (float*)d_out;
  unsigned short* Wr = (unsigned short*)d_ws;  // 2 MB of workspace

  hipLaunchKernelGGL(wconv, dim3(1024), dim3(256), 0, stream, fc, Wr);
  // grid: (N/128, M/128) = (2, 256) = 512 blocks = 2/CU (LDS-budget bound)
  hipLaunchKernelGGL(fkan_gemm, dim3(2, 256), dim3(256), 0, stream, x, Wr, bias, out);
}